// Round 9
// baseline (48975.623 us; speedup 1.0000x reference)
//
#include <hip/hip_runtime.h>

// HiPPO-LegS scan, chunked parallel formulation. L=1024,B=256,N=256 fp32.
//   x_t = A_t x_{t-1} + B_t*inp[t,b];  out[t,b,:] = x_t
// C=16 chunks of T=64:
//   Pass V (MODE 0): per-chunk zero-init scan -> v_end[c] (B,N)
//   Pass M (MODE 1): per-chunk cumulative matrix M^c, column-scan (x=e_j, u=0)
//   combine_all:     x_end[c] = M^c x_end[c-1] + v_end[c] (one launch, fp64 acc)
//   Pass F (MODE 2): re-scan chunk from x_start=x_end[c-1], write out
//
// ROUND 9 FIX: pad each k-group of the packed-triangle LDS layout to a
// 64-chunk slot boundary. R8's groups started mid-slot (3616, 7776), so
// phase-A staging spilled 32 chunks into G1 and phase-C into G3 -> ph1/ph3
// overwrote chunks of step t with step t+1 WHILE consuming them (drift error
// 0.0867). Padded bases GB={0,3648,6272,7872} (132 slots); slot phases align
// EXACTLY with consume phases: A[0,57) B[57,98) C[98,123) D[123,132).
// Pad chunks stage a dummy (A[0:4]) and are never consumed.
//
// Sync skeleton (per step, per wave), proven in R8:
//   ph0: vmcnt(2)[A,B(t) done] lgkm0 bar | issue D(t) | consume G0(t)
//   ph1: lgkm0 bar | issue A(t+1)        | consume G1(t)
//   ph2: vmcnt(5)[C(t) done] lgkm0 bar | issue B(t+1) | consume G2(t)
//   ph3: vmcnt(7)[D(t) done] lgkm0 bar | issue C(t+1) | consume G3(t)
//   end: lgkm0 bar | x update (published by next ph0's lgkm0+bar)

typedef float f32x4 __attribute__((ext_vector_type(4)));

#define LSTEPS  1024
#define BATCH   256
#define NDIM    256
#define NCH     16
#define TCH     64
#define NTHR    1024
#define NSLOT   132
#define XO      (NSLOT * 64 * 4)          // 33792 floats (A region)
#define XSTR    260
#define SMEMB   ((XO + 16 * XSTR) * 4)    // 151,808 B

__device__ __forceinline__ int tri4(int r) {   // prefix of per-row chunk counts
    const int a = r >> 2, bb = r & 3;
    return (a + 1) * (2 * a + bb);              // tri4(64)=544
}
__device__ __forceinline__ int offg(int r, int g) {  // row base within group g
    const int rho = r - 64 * g;
    return (rho < 64) ? tri4(rho) : 544 + 16 * (rho - 64);
}
template<int N> __device__ __forceinline__ void vmw() {
    asm volatile("s_waitcnt vmcnt(%0)" :: "n"(N) : "memory");
}
__device__ __forceinline__ void lgkm0() {
    asm volatile("s_waitcnt lgkmcnt(0)" ::: "memory");
}
__device__ __forceinline__ void bar() {
    __builtin_amdgcn_s_barrier();
    asm volatile("" ::: "memory");
}
__device__ __forceinline__ void dma16(const float* g, float* l) {
    __builtin_amdgcn_global_load_lds((const __attribute__((address_space(1))) void*)g,
                                     (__attribute__((address_space(3))) void*)l, 16, 0, 0);
}

// consume k-group G: kc in [16G,16G+16). High rows always active for G<2
// (kHiHi>=33); low rows only possible for G<2 (kHiLo<=32).
#define CONSUME(G) \
    _Pragma("unroll") \
    for (int kk = 0; kk < 16; ++kk) { \
        const int kc = (G) * 16 + kk; \
        if ((G) < 2 || kc < kHiHi) { \
            const f32x4 xv = *(const f32x4*)&xl[v * XSTR + kc * 4]; \
            const f32x4 a2 = *(const f32x4*)&smem[(cbh2[(G)] + kc) * 4]; \
            const f32x4 a3 = *(const f32x4*)&smem[(cbh3[(G)] + kc) * 4]; \
            acc2 = fmaf(a2[0], xv[0], acc2); acc2 = fmaf(a2[1], xv[1], acc2); \
            acc2 = fmaf(a2[2], xv[2], acc2); acc2 = fmaf(a2[3], xv[3], acc2); \
            acc3 = fmaf(a3[0], xv[0], acc3); acc3 = fmaf(a3[1], xv[1], acc3); \
            acc3 = fmaf(a3[2], xv[2], acc3); acc3 = fmaf(a3[3], xv[3], acc3); \
            if ((G) < 2 && kc < kHiLo) { \
                const f32x4 a0 = *(const f32x4*)&smem[(cbl0[(G)] + kc) * 4]; \
                const f32x4 a1 = *(const f32x4*)&smem[(cbl1[(G)] + kc) * 4]; \
                acc0 = fmaf(a0[0], xv[0], acc0); acc0 = fmaf(a0[1], xv[1], acc0); \
                acc0 = fmaf(a0[2], xv[2], acc0); acc0 = fmaf(a0[3], xv[3], acc0); \
                acc1 = fmaf(a1[0], xv[0], acc1); acc1 = fmaf(a1[1], xv[1], acc1); \
                acc1 = fmaf(a1[2], xv[2], acc1); acc1 = fmaf(a1[3], xv[3], acc1); \
            } \
        } \
    }

template<int MODE>   // 0: v_end scan, 1: M-column scan, 2: final scan -> out
__global__ __launch_bounds__(NTHR)
void scan_pass(const float* __restrict__ inp, const float* __restrict__ A,
               const float* __restrict__ Bst, float* __restrict__ out,
               float* __restrict__ vendP, float* __restrict__ MP,
               const float* __restrict__ xendP)
{
    extern __shared__ float smem[];
    float* xl = smem + XO;
    const int T    = threadIdx.x;
    const int lane = T & 63, wave = T >> 6;
    const int v    = T & 15,  q    = (T >> 4) & 3;
    const int u    = wave * 4 + q;
    const int blk  = blockIdx.x;
    const int c     = 2 * (blk & 7) + ((blk >> 3) & 1);  // 2 chunks per XCD
    const int slice = blk >> 4;
    const int b0    = slice * 16;      // batch base (M0/2) or column base (M1)
    const int vv = wave, n4 = lane * 4;       // copy mapping: wave <-> vector

    const int r0 = 2 * u, r1 = 2 * u + 1, r2 = 254 - 2 * u, r3 = 255 - 2 * u;
    const int kHiLo = (u >> 1) + 1;               // chunks in rows r0/r1 (<=32)
    const int kHiHi = (r2 >> 2) + 1;              // chunks in rows r2/r3 (>=33)

    // per-(row,group) consume bases, padded group bases GB={0,3648,6272,7872}
    const int GB[4] = {0, 3648, 6272, 7872};
    int cbl0[2], cbl1[2], cbh2[4], cbh3[4];
#pragma unroll
    for (int g = 0; g < 2; ++g) {
        cbl0[g] = GB[g] + offg(r0, g) - 16 * g;
        cbl1[g] = GB[g] + offg(r1, g) - 16 * g;
    }
#pragma unroll
    for (int g = 0; g < 4; ++g) {
        cbh2[g] = GB[g] + offg(r2, g) - 16 * g;
        cbh3[g] = GB[g] + offg(r3, g) - 16 * g;
    }

    // staging: 10 issues/wave; slot phases A[0,57) B[57,98) C[98,123) D[123,132)
    int gsrc[10], lbase[10];
#pragma unroll
    for (int p = 0; p < 10; ++p) {
        int slot;
        if (p < 4)      slot = (16 * p + wave) % 57;
        else if (p < 7) slot = 57 + (16 * (p - 4) + wave) % 41;
        else if (p < 9) slot = 98 + (16 * (p - 7) + wave) % 25;
        else            slot = 123 + (wave % 9);
        const int C = slot * 64 + lane;           // padded chunk index
        int g, gb, rs;
        if      (C >= 7872) { g = 3; gb = 7872; rs = 544;  }
        else if (C >= 6272) { g = 2; gb = 6272; rs = 1568; }
        else if (C >= 3648) { g = 1; gb = 3648; rs = 2592; }
        else                { g = 0; gb = 0;    rs = 3616; }
        const int cc = C - gb;
        int src = 0;                              // pad chunk: dummy A[0:4]
        if (cc < rs) {
            int r, kc;
            if (cc < 544) {
                int rl = 0, rh = 63;
                while (rl < rh) { const int mid = (rl + rh + 1) >> 1;
                                  if (tri4(mid) <= cc) rl = mid; else rh = mid - 1; }
                r = 64 * g + rl; kc = 16 * g + (cc - tri4(rl));
            } else {
                r = 64 * g + 64 + ((cc - 544) >> 4); kc = 16 * g + ((cc - 544) & 15);
            }
            src = r * NDIM + kc * 4;
        }
        gsrc[p]  = src;
        lbase[p] = slot * 256;
    }

    // x init
    {
        f32x4 xi = f32x4{0.f, 0.f, 0.f, 0.f};
        if (MODE == 2 && c > 0)
            xi = *(const f32x4*)&xendP[((size_t)(c - 1) * BATCH + b0 + vv) * NDIM + n4];
        *(f32x4*)&xl[vv * XSTR + n4] = xi;
        if (MODE == 1) {
            __syncthreads();
            if (T < 16) xl[T * XSTR + b0 + T] = 1.f;   // x^v = e_{b0+v}
        }
    }

    // prologue: stage all 4 groups of A(first step), full drain
    const float* At0 = A + (size_t)(c * TCH) * (NDIM * NDIM);
#pragma unroll
    for (int p = 0; p < 10; ++p) dma16(At0 + gsrc[p], smem + lbase[p]);
    asm volatile("s_waitcnt vmcnt(0) lgkmcnt(0)" ::: "memory");
    bar();

    for (int t = 0; t < TCH; ++t) {
        const int gt = c * TCH + t;
        const float* At = A + (size_t)gt * (NDIM * NDIM);
        const float* An = A + (size_t)((gt + 1 < LSTEPS) ? gt + 1 : gt) * (NDIM * NDIM);

        float acc0 = 0.f, acc1 = 0.f, acc2 = 0.f, acc3 = 0.f;
        float sIn = 0.f, sB0 = 0.f, sB1 = 0.f, sB2 = 0.f, sB3 = 0.f;

        // ---- ph0: consume G0(t). vmcnt(2): only C(t)'s 2 DMAs may remain ----
        vmw<2>(); lgkm0(); bar();
        dma16(At + gsrc[9], smem + lbase[9]);            // D(t), consumed ph3
        if (MODE == 2 && t > 0) {
            const f32x4 xo = *(const f32x4*)&xl[vv * XSTR + n4];
            *(f32x4*)&out[((size_t)(gt - 1) * BATCH + b0 + vv) * NDIM + n4] = xo;
        }
        if (MODE != 1) {
            sIn = inp[gt * BATCH + b0 + v];
            sB0 = Bst[gt * NDIM + r0]; sB1 = Bst[gt * NDIM + r1];
            sB2 = Bst[gt * NDIM + r2]; sB3 = Bst[gt * NDIM + r3];
        }
        CONSUME(0);

        // ---- ph1: consume G1(t) (covered by ph0's vmcnt(2)) ----
        lgkm0(); bar();
#pragma unroll
        for (int p = 0; p < 4; ++p) dma16(An + gsrc[p], smem + lbase[p]);   // A(t+1)
        CONSUME(1);

        // ---- ph2: consume G2(t). vmcnt(5): C(t) forced complete ----
        vmw<5>(); lgkm0(); bar();
#pragma unroll
        for (int p = 4; p < 7; ++p) dma16(An + gsrc[p], smem + lbase[p]);   // B(t+1)
        CONSUME(2);

        // ---- ph3: consume G3(t). vmcnt(7): D(t) forced complete ----
        vmw<7>(); lgkm0(); bar();
#pragma unroll
        for (int p = 7; p < 9; ++p) dma16(An + gsrc[p], smem + lbase[p]);   // C(t+1)
        CONSUME(3);

        float y0 = acc0, y1 = acc1, y2 = acc2, y3 = acc3;
        if (MODE != 1) {
            y0 = fmaf(sIn, sB0, y0); y1 = fmaf(sIn, sB1, y1);
            y2 = fmaf(sIn, sB2, y2); y3 = fmaf(sIn, sB3, y3);
        }
        lgkm0(); bar();   // all x/A reads of step t complete before x update
        xl[v * XSTR + r0] = y0; xl[v * XSTR + r1] = y1;
        xl[v * XSTR + r2] = y2; xl[v * XSTR + r3] = y3;
        // next ph0's lgkm0+bar publishes the new x
    }

    lgkm0(); bar();
    const f32x4 xf = *(const f32x4*)&xl[vv * XSTR + n4];
    if (MODE == 0) *(f32x4*)&vendP[((size_t)c * BATCH + b0 + vv) * NDIM + n4] = xf;
    if (MODE == 1) *(f32x4*)&MP[((size_t)c * NDIM + b0 + vv) * NDIM + n4] = xf;
    if (MODE == 2) *(f32x4*)&out[((size_t)(c * TCH + TCH - 1) * BATCH + b0 + vv) * NDIM + n4] = xf;
    asm volatile("s_waitcnt vmcnt(0)" ::: "memory");   // drain tail DMA
}

// x_end[c] = M^c x_end[c-1] + v_end[c]; 64 blocks x 4 batches, c sequential,
// fp64 accumulation. M col-major: M[c][j][i] = (M^c)_{i,j}
__global__ __launch_bounds__(1024)
void combine_all(const float* __restrict__ vend, const float* __restrict__ M,
                 float* __restrict__ xend)
{
    __shared__ float p[4][NDIM];
    const int i  = threadIdx.x & 255;
    const int bb = threadIdx.x >> 8;
    const int b  = blockIdx.x * 4 + bb;
    float x = vend[(size_t)b * NDIM + i];          // x_end[0] = v_end[0]
    xend[(size_t)b * NDIM + i] = x;
    for (int c = 1; c < NCH; ++c) {
        __syncthreads();
        p[bb][i] = x;
        __syncthreads();
        double acc = (double)vend[((size_t)c * BATCH + b) * NDIM + i];
        const float* Mc = M + (size_t)c * NDIM * NDIM;
#pragma unroll 8
        for (int j = 0; j < NDIM; ++j)
            acc += (double)Mc[j * NDIM + i] * (double)p[bb][j];
        x = (float)acc;
        xend[((size_t)c * BATCH + b) * NDIM + i] = x;
    }
}

// fallback (only if ws_size < 4MB): simple correct scan
__global__ __launch_bounds__(256)
void hippo_naive(const float* __restrict__ inp, const float* __restrict__ A,
                 const float* __restrict__ Bst, float* __restrict__ out)
{
    __shared__ float xs[2][NDIM];
    const int b = blockIdx.x, i = threadIdx.x;
    xs[0][i] = 0.f; __syncthreads();
    for (int t = 0; t < LSTEPS; ++t) {
        const float* At = A + (size_t)t * NDIM * NDIM + (size_t)i * NDIM;
        const float* xc = xs[t & 1];
        float acc = 0.f;
        for (int k = 0; k <= i; ++k) acc = fmaf(At[k], xc[k], acc);
        acc = fmaf(inp[t * BATCH + b], Bst[t * NDIM + i], acc);
        xs[(t & 1) ^ 1][i] = acc;
        out[((size_t)t * BATCH + b) * NDIM + i] = acc;
        __syncthreads();
    }
}

extern "C" void kernel_launch(void* const* d_in, const int* in_sizes, int n_in,
                              void* d_out, int out_size, void* d_ws, size_t ws_size,
                              hipStream_t stream) {
    const float* inp = (const float*)d_in[0];  // (L, BATCH)
    const float* A   = (const float*)d_in[1];  // (L, N, N)
    const float* Bst = (const float*)d_in[2];  // (L, N)
    float* out = (float*)d_out;                // (L, BATCH, N)

    const size_t needWs = (size_t)NCH * BATCH * NDIM * sizeof(float);  // 4 MB
    if (ws_size < needWs) {
        hipLaunchKernelGGL(hippo_naive, dim3(BATCH), dim3(NDIM), 0, stream,
                           inp, A, Bst, out);
        return;
    }
    // scratch inside out (stream-serialized; pass F overwrites all of out):
    float* vendP = out;                                 // [16][256][256]
    float* MP    = out + (size_t)NCH * BATCH * NDIM;    // [16][256][256] col-major
    float* xendP = (float*)d_ws;                        // [16][256][256]

    (void)hipFuncSetAttribute((const void*)scan_pass<0>,
                              hipFuncAttributeMaxDynamicSharedMemorySize, SMEMB);
    (void)hipFuncSetAttribute((const void*)scan_pass<1>,
                              hipFuncAttributeMaxDynamicSharedMemorySize, SMEMB);
    (void)hipFuncSetAttribute((const void*)scan_pass<2>,
                              hipFuncAttributeMaxDynamicSharedMemorySize, SMEMB);

    hipLaunchKernelGGL(scan_pass<0>, dim3(256), dim3(NTHR), SMEMB, stream,
                       inp, A, Bst, out, vendP, MP, (const float*)xendP);
    hipLaunchKernelGGL(scan_pass<1>, dim3(256), dim3(NTHR), SMEMB, stream,
                       inp, A, Bst, out, vendP, MP, (const float*)xendP);
    hipLaunchKernelGGL(combine_all, dim3(64), dim3(1024), 0, stream,
                       vendP, MP, xendP);
    hipLaunchKernelGGL(scan_pass<2>, dim3(256), dim3(NTHR), SMEMB, stream,
                       inp, A, Bst, out, vendP, MP, (const float*)xendP);
}